// Round 4
// baseline (370.395 us; speedup 1.0000x reference)
//
#include <hip/hip_runtime.h>
#include <hip/hip_bf16.h>

// B=2048, S=200, H=128, nh=2, L=7, d=64. Inputs/outputs fp32.
#define SEQ 200
#define HID 128
#define NLVL 7

// ws word offsets
#define WS_M16_W 0        // M16[4][128][128] bf16 = 65536 bf16 = 32768 words
#define WS_BF    32768    // Bf[4][128] fp32
#define WS_VB    33280    // vb[4][128] fp32
#define WS_CB    33792    // cb[4]
#define WS_WC    33796    // Wcomb[128][128] fp32 (staging)
#define WS_BC    50180    // bcomb[128]
#define WS_WORDS 50308

// per-batch qk image (written by precomp2, block-copied to LDS by mixer_main):
//   [0,2040)    qk-hi  30 rows x 68 words (bf16 pairs; rows 28-29 zeroed)
//   [2040,4080) qk-lo  30 rows x 68 words
//   [4080,4108) qb     28 floats
#define WS_QK    51200
#define QK_STRIDE 4112    // words per batch (16B-aligned)

#define SCST 212   // scores row stride (words): 212%32=20 spreads row banks; float2-aligned

typedef __attribute__((ext_vector_type(8))) short short8;   // 8 bf16 (4 VGPRs)
typedef __attribute__((ext_vector_type(4))) float f32x4;    // MFMA acc

__device__ __forceinline__ float bf_lo(unsigned u) { return __uint_as_float(u << 16); }
__device__ __forceinline__ float bf_hi(unsigned u) { return __uint_as_float(u & 0xffff0000u); }
__device__ __forceinline__ unsigned short bf_bits(float f) {
    __hip_bfloat16 h = __float2bfloat16(f);
    return *reinterpret_cast<unsigned short*>(&h);
}
__device__ __forceinline__ unsigned pack_bf(float a, float b) {
    return (unsigned)bf_bits(a) | ((unsigned)bf_bits(b) << 16);
}
__device__ __forceinline__ short8 cvt8(float4 a, float4 b) {
    short8 f;
    f[0] = (short)bf_bits(a.x); f[1] = (short)bf_bits(a.y);
    f[2] = (short)bf_bits(a.z); f[3] = (short)bf_bits(a.w);
    f[4] = (short)bf_bits(b.x); f[5] = (short)bf_bits(b.y);
    f[6] = (short)bf_bits(b.z); f[7] = (short)bf_bits(b.w);
    return f;
}

// ---- precompute 0: Wcomb = Wq @ Wlq, bcomb = Wq @ b_lq + bq ----
__global__ __launch_bounds__(256) void precomp0(
    const float* __restrict__ Wlq, const float* __restrict__ blq,
    const float* __restrict__ Wq,  const float* __restrict__ bq,
    float* __restrict__ ws)
{
    int id = blockIdx.x * 256 + threadIdx.x;  // [0, 16384)
    int r = id >> 7, j = id & 127;
    float acc = 0.f;
    #pragma unroll 8
    for (int c = 0; c < 128; ++c) acc += Wq[r * 128 + c] * Wlq[c * 128 + j];
    ws[WS_WC + id] = acc;
    if (id < 128) {
        float b = bq[id];
        #pragma unroll 8
        for (int c = 0; c < 128; ++c) b += Wq[id * 128 + c] * blq[c];
        ws[WS_BC + id] = b;
    }
}

// ---- precompute 1: M16[g][c][j] (bf16) = sum_d Wcomb[u*64+d][j]*Wk[par*64+d][c]; Bf, vb, cb ----
__global__ __launch_bounds__(256) void precomp1(
    const float* __restrict__ Wk, const float* __restrict__ bk, float* __restrict__ ws)
{
    int gid = blockIdx.x * 256 + threadIdx.x;
    if (gid < 65536) {
        int j = gid & 127, c = (gid >> 7) & 127, g = gid >> 14;
        int u = g >> 1, par = g & 1;
        const float* wc = ws + WS_WC + u * 64 * 128 + j;
        const float* wk = Wk + par * 64 * 128 + c;
        float acc = 0.f;
        #pragma unroll 8
        for (int d = 0; d < 64; ++d) acc += wc[d * 128] * wk[d * 128];
        ((__hip_bfloat16*)ws)[gid] = __float2bfloat16(acc);   // M16 at word 0
    } else if (gid < 66048) {
        int t = gid - 65536, c = t & 127, g = t >> 7;
        int u = g >> 1, par = g & 1;
        float acc = 0.f;
        #pragma unroll 8
        for (int d = 0; d < 64; ++d)
            acc += ws[WS_BC + u * 64 + d] * Wk[(par * 64 + d) * 128 + c];
        ws[WS_BF + t] = acc;
    } else if (gid < 66560) {
        int t = gid - 66048, j = t & 127, g = t >> 7;
        int u = g >> 1, par = g & 1;
        float acc = 0.f;
        #pragma unroll 8
        for (int d = 0; d < 64; ++d)
            acc += ws[WS_WC + (u * 64 + d) * 128 + j] * bk[par * 64 + d];
        ws[WS_VB + t] = acc;
    } else if (gid < 66564) {
        int g = gid - 66560, u = g >> 1, par = g & 1;
        float acc = 0.f;
        for (int d = 0; d < 64; ++d)
            acc += ws[WS_BC + u * 64 + d] * bk[par * 64 + d];
        ws[WS_CB + g] = acc;
    }
}

// ---- precompute 2: per-batch qk image (level gather+cumsum, qk MFMA, qb) -> ws ----
// 2048 independent blocks at full occupancy: latency chains overlap, throughput-bound.
__global__ __launch_bounds__(512, 8) void precomp2(
    const float* __restrict__ emb, const int* __restrict__ seq_len,
    float* __restrict__ ws)
{
    const int b    = blockIdx.x;
    const int tid  = threadIdx.x;
    const int wave = tid >> 6, lane = tid & 63;
    const int ln   = lane & 15, quad = lane >> 4;

    __shared__ __align__(16) float s_lvl[NLVL * 128];
    __shared__ __align__(16) short s_lvl16[16 * 136];  // rows 7..15 junk; junk outputs discarded

    unsigned* wq = (unsigned*)ws + WS_QK + (size_t)b * QK_STRIDE;
    const float* embb = emb + (size_t)b * SEQ * HID;
    const int len = seq_len[b];

    // stage 1: level gather + cumsum
    if (tid < HID) {
        float e[NLVL];
        #pragma unroll
        for (int j = 0; j < NLVL; ++j) {
            int idx = len - (j + 1);
            if (idx < 0) idx = SEQ - 1;  // torch clamp(-1) + wrap
            e[j] = embb[(size_t)idx * HID + tid];
        }
        float acc = 0.f;
        #pragma unroll
        for (int j = 0; j < NLVL; ++j) {
            acc += e[j];
            s_lvl[j * HID + tid] = acc;
            s_lvl16[j * 136 + tid] = (short)bf_bits(acc);
        }
    } else if (tid >= 448) {
        // zero pad rows 28,29 of hi and lo images
        int t = tid - 448;
        for (int i = t; i < 136; i += 64) {
            wq[1904 + i] = 0u;          // hi rows 28-29
            wq[3944 + i] = 0u;          // lo rows 28-29
        }
    }
    __syncthreads();

    // stage 2: qk = lvl @ M^T via MFMA; write bf16 hi+lo image + qb to ws
    {
        const int g = wave >> 1, halfm = wave & 1;
        const int mrow = ln;
        short8 bfrag[4];
        #pragma unroll
        for (int k = 0; k < 4; ++k)
            bfrag[k] = *(const short8*)(s_lvl16 + mrow * 136 + k * 32 + quad * 8);
        const short* M16 = (const short*)ws;  // [4][128][128] bf16
        #pragma unroll
        for (int mt = 0; mt < 4; ++mt) {
            int mtile = halfm * 4 + mt;
            int cbase = mtile * 16 + quad * 4;
            f32x4 acc;
            #pragma unroll
            for (int r = 0; r < 4; ++r) acc[r] = ws[WS_BF + g * 128 + cbase + r];
            const short* Ab = M16 + (g * 128 + mtile * 16 + mrow) * 128;
            #pragma unroll
            for (int k = 0; k < 4; ++k) {
                short8 afrag = *(const short8*)(Ab + k * 32 + quad * 8);
                acc = __builtin_amdgcn_mfma_f32_16x16x32_bf16(afrag, bfrag[k], acc, 0, 0, 0);
            }
            if (mrow < NLVL) {   // D cols n>=7 junk
                int qrow = mrow * 4 + g;       // stage-3 B row index (h*14 + r)
                unsigned h01 = pack_bf(acc[0], acc[1]);
                unsigned h23 = pack_bf(acc[2], acc[3]);
                float l0 = acc[0] - bf_lo(h01), l1 = acc[1] - bf_hi(h01);
                float l2 = acc[2] - bf_lo(h23), l3 = acc[3] - bf_hi(h23);
                int woff = qrow * 68 + mtile * 8 + quad * 2;
                *(uint2*)(wq + woff)        = make_uint2(h01, h23);
                *(uint2*)(wq + 2040 + woff) = make_uint2(pack_bf(l0, l1), pack_bf(l2, l3));
            }
        }
        // parallel qb: 28 rows x 16 lanes, stride-16 (conflict-free), shfl reduce
        if (tid < 448) {
            int grp = tid >> 4, sub = tid & 15;   // grp in [0,28)
            int gg = grp & 3, L = grp >> 2;
            const float* vb = ws + WS_VB + gg * 128;
            const float* lv = s_lvl + L * 128;
            float acc = 0.f;
            #pragma unroll
            for (int k = 0; k < 8; ++k) {
                int j = sub + 16 * k;
                acc += lv[j] * vb[j];
            }
            acc += __shfl_xor(acc, 1, 16);
            acc += __shfl_xor(acc, 2, 16);
            acc += __shfl_xor(acc, 4, 16);
            acc += __shfl_xor(acc, 8, 16);
            if (sub == 0) ((float*)(wq + 4080))[grp] = acc + ws[WS_CB + gg];
        }
    }
}

// ---- main kernel: one block per batch, 512 threads, ~32 KB LDS -> 4 blocks/CU ----
// Round-4: stages 1-2 hoisted to precomp2. Main = {qk copy -> scores MFMA with
// fused exp/denominator -> LP-pool -> weighted sum -> out}. 4 barriers, no
// cross-barrier register state (spill-proof), round-1's proven stage-3 form.
__global__ __launch_bounds__(512, 8) void mixer_main(
    const int* __restrict__ item_seq,
    const float* __restrict__ emb,
    const float* __restrict__ ws,
    float* __restrict__ out)
{
    const int b    = blockIdx.x;
    const int tid  = threadIdx.x;
    const int wave = tid >> 6, lane = tid & 63;
    const int ln   = lane & 15, quad = lane >> 4;

    // LDS (~32 KB total)
    __shared__ __align__(16) unsigned s_qkbuf[4108]; // [0,2040) hi | [2040,4080) lo | [4080,4108) qb
    __shared__ __align__(16) float s_scores[14 * SCST];   // E = exp(sigmoid(score))
    __shared__ float s_denom[14];
    __shared__ __align__(16) float s_A[2 * SEQ];
    __shared__ __align__(16) float s_red[512];

    short* s_qkhi = (short*)s_qkbuf;
    float* s_qb   = (float*)(s_qkbuf + 4080);

    const float* embb = emb + (size_t)b * SEQ * HID;
    const unsigned* qsrc = (const unsigned*)ws + WS_QK + (size_t)b * QK_STRIDE;

    // ---- stage A: qk image -> LDS (coalesced uint4), zero denoms ----
    {
        const uint4* src = (const uint4*)qsrc;
        uint4* dst = (uint4*)s_qkbuf;
        for (int i = tid; i < 1027; i += 512) dst[i] = src[i];
        if (tid < 14) s_denom[tid] = 0.f;
    }
    __syncthreads();

    // ---- stage 3: scores via MFMA; fused sigmoid -> E=exp(sig) -> denom atomics ----
    // D: col(lane&15)=qk-row r, row(quad*4+i)=gq-local. score(h*7+(r>>1), 2*gq+(r&1)).
    {
        #pragma unroll 1
        for (int t = wave; t < 14; t += 8) {
            const int h = t / 7, mtile = t % 7;
            int gqrow = mtile * 16 + ln;
            int rowg = h * 100 + (gqrow < 100 ? gqrow : 99); // clamp avoids OOB at h=1,m=6
            const float* Arow = embb + (size_t)rowg * HID;
            float qbv = (ln < 14) ? s_qb[h * 14 + ln] : 0.f;
            f32x4 acc;
            acc[0] = qbv; acc[1] = qbv; acc[2] = qbv; acc[3] = qbv;
            #pragma unroll 2
            for (int kk = 0; kk < 4; ++kk) {
                float4 v0 = *(const float4*)(Arow + kk * 32 + quad * 8);
                float4 v1 = *(const float4*)(Arow + kk * 32 + quad * 8 + 4);
                short8 afrag = cvt8(v0, v1);
                const int boff = (h * 14 + ln) * 136 + kk * 32 + quad * 8;
                short8 bhi = *(const short8*)(s_qkhi + boff);
                short8 blo = *(const short8*)(s_qkhi + 2040 * 2 + boff);  // lo image
                acc = __builtin_amdgcn_mfma_f32_16x16x32_bf16(afrag, bhi, acc, 0, 0, 0);
                acc = __builtin_amdgcn_mfma_f32_16x16x32_bf16(afrag, blo, acc, 0, 0, 0);
            }
            float part = 0.f;
            if (ln < 14) {
                int srow = (h * 7 + (ln >> 1)) * SCST, par = ln & 1;
                #pragma unroll
                for (int i = 0; i < 4; ++i) {
                    int gq = mtile * 16 + quad * 4 + i;
                    if (gq < 100) {
                        float sg = 1.f / (1.f + __expf(-acc[i]));
                        float E = __expf(sg);
                        s_scores[srow + 2 * gq + par] = E;
                        part += E;
                    }
                }
            }
            part += __shfl_xor(part, 16, 64);
            part += __shfl_xor(part, 32, 64);
            part += __shfl_xor(part, 1, 64);
            if (quad == 0 && ln < 14 && (ln & 1) == 0)
                atomicAdd(&s_denom[h * 7 + (ln >> 1)], part);
        }
    }
    __syncthreads();

    // ---- stage 5: softmax-1 normalize + LP-pool (p=4) + mask + exp ----
    if (tid < 2 * SEQ) {
        int h = tid / SEQ, s2 = tid % SEQ;
        float ssum = 0.f;
        #pragma unroll
        for (int l = 0; l < NLVL; ++l) {
            float v = __fdividef(s_scores[(h * NLVL + l) * SCST + s2],
                                 s_denom[h * NLVL + l]);
            float v2 = v * v;
            ssum += v2 * v2;
        }
        float A = sqrtf(sqrtf(ssum));
        int m = item_seq[(size_t)b * SEQ + s2];
        s_A[tid] = (m > 0) ? __expf(A) : 0.f;
    }
    __syncthreads();

    // ---- stage 6: weighted sum over s (4-way split), emb re-read (L2/LLC-warm) ----
    {
        int c = tid & 127, qq = tid >> 7;
        int h = c >> 6;
        const float* wv = s_A + h * SEQ + qq * 50;
        const float* eg = embb + (size_t)(qq * 50) * HID + c;
        float acc = 0.f;
        #pragma unroll 10
        for (int s = 0; s < 50; ++s)
            acc += wv[s] * eg[(size_t)s * HID];
        s_red[tid] = acc;
    }
    __syncthreads();

    // ---- stage 7: combine + softmax-2 denominator folded in (wave-local shuffle) ----
    if (tid < HID) {
        int h = tid >> 6;   // whole wave shares h
        const float* row = s_A + h * SEQ;
        float sum = row[lane] + row[lane + 64] + row[lane + 128]
                  + ((lane + 192 < 200) ? row[lane + 192] : 0.f);
        #pragma unroll
        for (int mm = 1; mm < 64; mm <<= 1) sum += __shfl_xor(sum, mm, 64);
        float inv = 1.f / sum;
        float tot = (s_red[tid] + s_red[tid + 128] + s_red[tid + 256] + s_red[tid + 384]) * inv;
        out[(size_t)b * HID + tid] = tot;
    }
}

// ---- fallback (ws too small): proven monolithic fp32 kernel ----
__global__ __launch_bounds__(256) void mixer_fallback(
    const int* __restrict__ item_seq, const float* __restrict__ emb,
    const int* __restrict__ seq_len,
    const float* __restrict__ Wlq, const float* __restrict__ blq,
    const float* __restrict__ Wq,  const float* __restrict__ bq,
    const float* __restrict__ Wk,  const float* __restrict__ bk,
    float* __restrict__ out)
{
    const int b = blockIdx.x, tid = threadIdx.x;
    __shared__ unsigned s_embu[SEQ * 65];
    __shared__ float s_qk[28 * 128];
    __shared__ float s_qb[28];
    __shared__ float s_tmp[2800];
    __shared__ float s_A[400];
    __shared__ float s_red[256];
    __shared__ float s_inv[2];

    {
        const float4* src = (const float4*)(emb + (size_t)b * SEQ * HID);
        for (int i = tid; i < SEQ * 32; i += 256) {
            int row = i >> 5, j = i & 31;
            float4 v = src[i];
            unsigned* dst = s_embu + row * 65 + 2 * j;
            dst[0] = pack_bf(v.x, v.y);
            dst[1] = pack_bf(v.z, v.w);
        }
    }
    const int len = seq_len[b];
    if (tid < HID) {
        float acc = 0.f;
        for (int j = 0; j < NLVL; ++j) {
            int idx = len - (j + 1);
            if (idx < 0) idx = SEQ - 1;
            acc += emb[(size_t)b * SEQ * HID + (size_t)idx * HID + tid];
            s_tmp[j * HID + tid] = acc;
        }
    }
    __syncthreads();
    for (int t = tid; t < NLVL * HID; t += 256) {
        int l = t >> 7, c = t & 127;
        const float* x = s_tmp + l * HID;
        float acc = blq[c];
        #pragma unroll 8
        for (int k = 0; k < HID; ++k) acc += x[k] * Wlq[c * HID + k];
        s_tmp[896 + t] = acc;
    }
    __syncthreads();
    for (int t = tid; t < NLVL * HID; t += 256) {
        int l = t >> 7, c = t & 127;
        const float* x = s_tmp + 896 + l * HID;
        float acc = bq[c];
        #pragma unroll 8
        for (int k = 0; k < HID; ++k) acc += x[k] * Wq[c * HID + k];
        s_tmp[t] = acc;
    }
    __syncthreads();
    for (int o = tid; o < 28 * 128; o += 256) {
        int qrow = o >> 7, c = o & 127;
        int hl = qrow >> 1, par = qrow & 1;
        const float* qv = s_tmp + hl * 64;
        float acc = 0.f;
        #pragma unroll 8
        for (int d2 = 0; d2 < 64; ++d2) acc += qv[d2] * Wk[(par * 64 + d2) * HID + c];
        s_qk[qrow * 128 + c] = acc;
    }
    if (tid < 28) {
        int hl = tid >> 1, par = tid & 1;
        float acc = 0.f;
        for (int d2 = 0; d2 < 64; ++d2) acc += s_tmp[hl * 64 + d2] * bk[par * 64 + d2];
        s_qb[tid] = acc;
    }
    __syncthreads();
    for (int o = tid; o < 700; o += 256) {
        int hl = o / 50, g = o % 50;
        int h = (hl >= 7) ? 1 : 0;
        int rA = h * 100 + g, rB = rA + 50;
        const unsigned* eA = s_embu + rA * 65;
        const unsigned* eB = s_embu + rB * 65;
        const float* k0 = s_qk + (hl * 2) * 128;
        const float* k1 = s_qk + (hl * 2 + 1) * 128;
        float a0 = 0.f, a1 = 0.f, c0a = 0.f, c1a = 0.f;
        #pragma unroll 4
        for (int kk = 0; kk < 64; ++kk) {
            unsigned uA = eA[kk], uB = eB[kk];
            float2 w0 = *(const float2*)(k0 + 2 * kk);
            float2 w1 = *(const float2*)(k1 + 2 * kk);
            float alo = bf_lo(uA), ahi = bf_hi(uA);
            float blo = bf_lo(uB), bhi = bf_hi(uB);
            a0 += alo * w0.x + ahi * w0.y;  a1 += alo * w1.x + ahi * w1.y;
            c0a += blo * w0.x + bhi * w0.y; c1a += blo * w1.x + bhi * w1.y;
        }
        float qb0 = s_qb[hl * 2], qb1 = s_qb[hl * 2 + 1];
        float* row = s_tmp + hl * 200;
        row[2 * g]       = 1.f / (1.f + __expf(-(a0 + qb0)));
        row[2 * g + 1]   = 1.f / (1.f + __expf(-(a1 + qb1)));
        row[2 * g + 100] = 1.f / (1.f + __expf(-(c0a + qb0)));
        row[2 * g + 101] = 1.f / (1.f + __expf(-(c1a + qb1)));
    }
    __syncthreads();
    const int wave = tid >> 6, lane = tid & 63;
    for (int r = wave; r < 14; r += 4) {
        float* row = s_tmp + r * 200;
        float e0 = __expf(row[lane]), e1 = __expf(row[lane + 64]);
        float e2 = __expf(row[lane + 128]);
        float e3 = (lane + 192 < 200) ? __expf(row[lane + 192]) : 0.f;
        float sum = e0 + e1 + e2 + e3;
        #pragma unroll
        for (int m = 1; m < 64; m <<= 1) sum += __shfl_xor(sum, m, 64);
        float inv = 1.f / sum;
        row[lane] = e0 * inv; row[lane + 64] = e1 * inv; row[lane + 128] = e2 * inv;
        if (lane + 192 < 200) row[lane + 192] = e3 * inv;
    }
    __syncthreads();
    for (int o = tid; o < 2 * SEQ; o += 256) {
        int h = o / SEQ, s2 = o % SEQ;
        float ssum = 0.f;
        #pragma unroll
        for (int l = 0; l < NLVL; ++l) {
            float v = s_tmp[(h * NLVL + l) * 200 + s2];
            float v2 = v * v; ssum += v2 * v2;
        }
        float A = sqrtf(sqrtf(ssum));
        s_A[o] = (item_seq[(size_t)b * SEQ + s2] > 0) ? __expf(A) : 0.f;
    }
    __syncthreads();
    if (wave < 2) {
        const float* row = s_A + wave * SEQ;
        float sum = row[lane] + row[lane + 64] + row[lane + 128]
                  + ((lane + 192 < 200) ? row[lane + 192] : 0.f);
        #pragma unroll
        for (int m = 1; m < 64; m <<= 1) sum += __shfl_xor(sum, m, 64);
        if (lane == 0) s_inv[wave] = 1.f / sum;
    }
    __syncthreads();
    {
        int c = tid & 127, halfb = tid >> 7;
        int h = c >> 6;
        const float* wv = s_A + h * SEQ + halfb * 100;
        float acc = 0.f;
        #pragma unroll 4
        for (int s2 = 0; s2 < 100; ++s2) {
            unsigned u = s_embu[(halfb * 100 + s2) * 65 + (c >> 1)];
            acc += wv[s2] * ((c & 1) ? bf_hi(u) : bf_lo(u));
        }
        s_red[tid] = acc;
    }
    __syncthreads();
    if (tid < HID) {
        int h = tid >> 6;
        out[(size_t)b * HID + tid] = (s_red[tid] + s_red[tid + 128]) * s_inv[h];
    }
}

extern "C" void kernel_launch(void* const* d_in, const int* in_sizes, int n_in,
                              void* d_out, int out_size, void* d_ws, size_t ws_size,
                              hipStream_t stream) {
    const int* item_seq = (const int*)d_in[0];
    const float* emb    = (const float*)d_in[1];
    const int* seq_len  = (const int*)d_in[2];
    const float* Wlq    = (const float*)d_in[3];
    const float* blq    = (const float*)d_in[4];
    const float* Wq     = (const float*)d_in[5];
    const float* bq     = (const float*)d_in[6];
    const float* Wk     = (const float*)d_in[7];
    const float* bk     = (const float*)d_in[8];
    float* out          = (float*)d_out;
    const int B = in_sizes[2];  // 2048

    const size_t need = ((size_t)WS_QK + (size_t)B * QK_STRIDE) * 4;
    if (ws_size >= need) {
        float* ws = (float*)d_ws;
        precomp0<<<64, 256, 0, stream>>>(Wlq, blq, Wq, bq, ws);
        precomp1<<<261, 256, 0, stream>>>(Wk, bk, ws);
        precomp2<<<B, 512, 0, stream>>>(emb, seq_len, ws);
        mixer_main<<<B, 512, 0, stream>>>(item_seq, emb, ws, out);
    } else {
        mixer_fallback<<<B, 256, 0, stream>>>(item_seq, emb, seq_len, Wlq, blq, Wq, bq, Wk, bk, out);
    }
}

// Round 5
// 344.481 us; speedup vs baseline: 1.0752x; 1.0752x over previous
//
#include <hip/hip_runtime.h>
#include <hip/hip_bf16.h>

// B=2048, S=200, H=128, nh=2, L=7, d=64. Inputs/outputs fp32.
#define SEQ 200
#define HID 128
#define NLVL 7

// ws word offsets
#define WS_M16_W 0        // M16[4][128][128] bf16 = 65536 bf16 = 32768 words
#define WS_BF    32768    // Bf[4][128] fp32
#define WS_VB    33280    // vb[4][128] fp32
#define WS_CB    33792    // cb[4]
#define WS_WC    33796    // Wcomb[128][128] fp32 (staging)
#define WS_BC    50180    // bcomb[128]
#define WS_WORDS 50308

#define SCST 212   // scores row stride (words): 212%32=20 spreads row banks; float2-aligned

typedef __attribute__((ext_vector_type(8))) short short8;   // 8 bf16 (4 VGPRs)
typedef __attribute__((ext_vector_type(4))) float f32x4;    // MFMA acc

__device__ __forceinline__ float bf_lo(unsigned u) { return __uint_as_float(u << 16); }
__device__ __forceinline__ float bf_hi(unsigned u) { return __uint_as_float(u & 0xffff0000u); }
__device__ __forceinline__ unsigned short bf_bits(float f) {
    __hip_bfloat16 h = __float2bfloat16(f);
    return *reinterpret_cast<unsigned short*>(&h);
}
__device__ __forceinline__ unsigned pack_bf(float a, float b) {
    return (unsigned)bf_bits(a) | ((unsigned)bf_bits(b) << 16);
}
__device__ __forceinline__ short8 cvt8(float4 a, float4 b) {
    short8 f;
    f[0] = (short)bf_bits(a.x); f[1] = (short)bf_bits(a.y);
    f[2] = (short)bf_bits(a.z); f[3] = (short)bf_bits(a.w);
    f[4] = (short)bf_bits(b.x); f[5] = (short)bf_bits(b.y);
    f[6] = (short)bf_bits(b.z); f[7] = (short)bf_bits(b.w);
    return f;
}

// ---- precompute 0: Wcomb = Wq @ Wlq, bcomb = Wq @ b_lq + bq ----
__global__ __launch_bounds__(256) void precomp0(
    const float* __restrict__ Wlq, const float* __restrict__ blq,
    const float* __restrict__ Wq,  const float* __restrict__ bq,
    float* __restrict__ ws)
{
    int id = blockIdx.x * 256 + threadIdx.x;  // [0, 16384)
    int r = id >> 7, j = id & 127;
    float acc = 0.f;
    #pragma unroll 8
    for (int c = 0; c < 128; ++c) acc += Wq[r * 128 + c] * Wlq[c * 128 + j];
    ws[WS_WC + id] = acc;
    if (id < 128) {
        float b = bq[id];
        #pragma unroll 8
        for (int c = 0; c < 128; ++c) b += Wq[id * 128 + c] * blq[c];
        ws[WS_BC + id] = b;
    }
}

// ---- precompute 1: M16[g][c][j] (bf16) = sum_d Wcomb[u*64+d][j]*Wk[par*64+d][c]; Bf, vb, cb ----
__global__ __launch_bounds__(256) void precomp1(
    const float* __restrict__ Wk, const float* __restrict__ bk, float* __restrict__ ws)
{
    int gid = blockIdx.x * 256 + threadIdx.x;
    if (gid < 65536) {
        int j = gid & 127, c = (gid >> 7) & 127, g = gid >> 14;
        int u = g >> 1, par = g & 1;
        const float* wc = ws + WS_WC + u * 64 * 128 + j;
        const float* wk = Wk + par * 64 * 128 + c;
        float acc = 0.f;
        #pragma unroll 8
        for (int d = 0; d < 64; ++d) acc += wc[d * 128] * wk[d * 128];
        ((__hip_bfloat16*)ws)[gid] = __float2bfloat16(acc);   // M16 at word 0
    } else if (gid < 66048) {
        int t = gid - 65536, c = t & 127, g = t >> 7;
        int u = g >> 1, par = g & 1;
        float acc = 0.f;
        #pragma unroll 8
        for (int d = 0; d < 64; ++d)
            acc += ws[WS_BC + u * 64 + d] * Wk[(par * 64 + d) * 128 + c];
        ws[WS_BF + t] = acc;
    } else if (gid < 66560) {
        int t = gid - 66048, j = t & 127, g = t >> 7;
        int u = g >> 1, par = g & 1;
        float acc = 0.f;
        #pragma unroll 8
        for (int d = 0; d < 64; ++d)
            acc += ws[WS_WC + (u * 64 + d) * 128 + j] * bk[par * 64 + d];
        ws[WS_VB + t] = acc;
    } else if (gid < 66564) {
        int g = gid - 66560, u = g >> 1, par = g & 1;
        float acc = 0.f;
        for (int d = 0; d < 64; ++d)
            acc += ws[WS_BC + u * 64 + d] * bk[par * 64 + d];
        ws[WS_CB + g] = acc;
    }
}

// ---- main kernel: one block per batch, 512 threads, ~32 KB LDS -> 4 blocks/CU ----
// Round-5: monolithic round-1 skeleton (proven 123.6 us, VGPR 32, no scratch)
// + two validated fusions: (a) stage-3/4 fused (store E=exp(sigmoid), denom via
// shfl+LDS atomics -> one fewer barrier + no scores re-read pass), (b) parallel
// qb dot (28x16 lanes, shfl reduce). No held-register prefetch (spills at 8/EU),
// no qk HBM roundtrip (precomp2 cost > its benefit, round 4). 5 barriers.
__global__ __launch_bounds__(512, 8) void mixer_main(
    const int* __restrict__ item_seq,
    const float* __restrict__ emb,
    const int* __restrict__ seq_len,
    const float* __restrict__ ws,
    float* __restrict__ out)
{
    const int b    = blockIdx.x;
    const int tid  = threadIdx.x;
    const int wave = tid >> 6, lane = tid & 63;
    const int ln   = lane & 15, quad = lane >> 4;

    // LDS (~32 KB total)
    __shared__ __align__(16) short s_qkhi[30 * 136];   // qk bf16 hi, rows 0..27 (+2 zero pad)
    __shared__ __align__(16) short s_qklo[30 * 136];   // qk bf16 lo residual
    __shared__ __align__(16) char  s_region[14 * SCST * 4]; // overlay: lvl/lvl16 (st1-2) | E-scores (st3+)
    __shared__ float s_qb[28];
    __shared__ float s_denom[14];
    __shared__ __align__(16) float s_A[2 * SEQ];
    __shared__ __align__(16) float s_red[512];

    float* s_scores = (float*)s_region;              // [14][SCST] fp32: E = exp(sigmoid)
    float* s_lvl    = (float*)s_region;              // [7][128] fp32
    short* s_lvl16  = (short*)(s_region + 3584);     // [16][136] bf16 (rows 7..15 junk, outputs discarded)

    const float* embb = emb + (size_t)b * SEQ * HID;
    const int len = seq_len[b];

    // ---- stage 1: level gather + cumsum (tid<128); zero qk pads / denoms ----
    if (tid < HID) {
        float e[NLVL];
        #pragma unroll
        for (int j = 0; j < NLVL; ++j) {
            int idx = len - (j + 1);
            if (idx < 0) idx = SEQ - 1;  // torch clamp(-1) + wrap
            e[j] = embb[(size_t)idx * HID + tid];
        }
        float acc = 0.f;
        #pragma unroll
        for (int j = 0; j < NLVL; ++j) {
            acc += e[j];
            s_lvl[j * HID + tid] = acc;
            s_lvl16[j * 136 + tid] = (short)bf_bits(acc);
        }
    } else if (tid < 196) {
        // rows 28,29 of qk (read by h=1 B-frags for junk cols 14,15) -> zero
        int t = tid - 128;   // 68 threads x uint2 = 272 shorts = 2 rows x 136
        ((uint2*)(s_qkhi + 28 * 136))[t] = make_uint2(0u, 0u);
        ((uint2*)(s_qklo + 28 * 136))[t] = make_uint2(0u, 0u);
    } else if (tid < 210) {
        s_denom[tid - 196] = 0.f;
    }
    __syncthreads();

    // ---- stage 2: qk = lvl @ M^T via MFMA (bf16 hi+lo); parallel qb dots ----
    {
        const int g = wave >> 1, halfm = wave & 1;
        const int mrow = ln;
        short8 bfrag[4];
        #pragma unroll
        for (int k = 0; k < 4; ++k)
            bfrag[k] = *(const short8*)(s_lvl16 + mrow * 136 + k * 32 + quad * 8);
        const short* M16 = (const short*)ws;  // [4][128][128] bf16
        #pragma unroll
        for (int mt = 0; mt < 4; ++mt) {
            int mtile = halfm * 4 + mt;
            int cbase = mtile * 16 + quad * 4;
            f32x4 acc;
            #pragma unroll
            for (int r = 0; r < 4; ++r) acc[r] = ws[WS_BF + g * 128 + cbase + r];
            const short* Ab = M16 + (g * 128 + mtile * 16 + mrow) * 128;
            #pragma unroll
            for (int k = 0; k < 4; ++k) {
                short8 afrag = *(const short8*)(Ab + k * 32 + quad * 8);
                acc = __builtin_amdgcn_mfma_f32_16x16x32_bf16(afrag, bfrag[k], acc, 0, 0, 0);
            }
            if (mrow < NLVL) {   // D cols n>=7 are junk
                int qrow = mrow * 4 + g;       // stage-3 B row index (h*14 + r)
                unsigned h01 = pack_bf(acc[0], acc[1]);
                unsigned h23 = pack_bf(acc[2], acc[3]);
                float l0 = acc[0] - bf_lo(h01), l1 = acc[1] - bf_hi(h01);
                float l2 = acc[2] - bf_lo(h23), l3 = acc[3] - bf_hi(h23);
                *(uint2*)(s_qkhi + qrow * 136 + cbase) = make_uint2(h01, h23);
                *(uint2*)(s_qklo + qrow * 136 + cbase) = make_uint2(pack_bf(l0, l1), pack_bf(l2, l3));
            }
        }
        // parallel qb: 28 rows x 16 lanes, stride-16 lv reads (conflict-free), shfl reduce
        if (tid < 448) {
            int grp = tid >> 4, sub = tid & 15;   // grp in [0,28)
            int gg = grp & 3, L = grp >> 2;
            const float* vb = ws + WS_VB + gg * 128;
            const float* lv = s_lvl + L * 128;
            float acc = 0.f;
            #pragma unroll
            for (int k = 0; k < 8; ++k) {
                int j = sub + 16 * k;
                acc += lv[j] * vb[j];
            }
            acc += __shfl_xor(acc, 1, 16);
            acc += __shfl_xor(acc, 2, 16);
            acc += __shfl_xor(acc, 4, 16);
            acc += __shfl_xor(acc, 8, 16);
            if (sub == 0) s_qb[grp] = acc + ws[WS_CB + gg];
        }
    }
    __syncthreads();

    // ---- stage 3: scores via MFMA; fused sigmoid -> E=exp(sig) -> denom atomics ----
    // D: col(lane&15)=qk-row r, row(quad*4+i)=gq-local. score(h*7+(r>>1), 2*gq+(r&1)).
    {
        #pragma unroll 1
        for (int t = wave; t < 14; t += 8) {
            const int h = t / 7, mtile = t % 7;
            int gqrow = mtile * 16 + ln;
            int rowg = h * 100 + (gqrow < 100 ? gqrow : 99); // clamp avoids OOB at h=1,m=6
            const float* Arow = embb + (size_t)rowg * HID;
            float qbv = (ln < 14) ? s_qb[h * 14 + ln] : 0.f;
            f32x4 acc;
            acc[0] = qbv; acc[1] = qbv; acc[2] = qbv; acc[3] = qbv;
            #pragma unroll 2
            for (int kk = 0; kk < 4; ++kk) {
                float4 v0 = *(const float4*)(Arow + kk * 32 + quad * 8);
                float4 v1 = *(const float4*)(Arow + kk * 32 + quad * 8 + 4);
                short8 afrag = cvt8(v0, v1);
                const int boff = (h * 14 + ln) * 136 + kk * 32 + quad * 8;
                short8 bhi = *(const short8*)(s_qkhi + boff);
                short8 blo = *(const short8*)(s_qklo + boff);
                acc = __builtin_amdgcn_mfma_f32_16x16x32_bf16(afrag, bhi, acc, 0, 0, 0);
                acc = __builtin_amdgcn_mfma_f32_16x16x32_bf16(afrag, blo, acc, 0, 0, 0);
            }
            float part = 0.f;
            if (ln < 14) {
                int srow = (h * 7 + (ln >> 1)) * SCST, par = ln & 1;
                #pragma unroll
                for (int i = 0; i < 4; ++i) {
                    int gq = mtile * 16 + quad * 4 + i;
                    if (gq < 100) {
                        float sg = 1.f / (1.f + __expf(-acc[i]));
                        float E = __expf(sg);
                        s_scores[srow + 2 * gq + par] = E;
                        part += E;
                    }
                }
            }
            part += __shfl_xor(part, 16, 64);
            part += __shfl_xor(part, 32, 64);
            part += __shfl_xor(part, 1, 64);
            if (quad == 0 && ln < 14 && (ln & 1) == 0)
                atomicAdd(&s_denom[h * 7 + (ln >> 1)], part);
        }
    }
    __syncthreads();

    // ---- stage 5: softmax-1 normalize + LP-pool (p=4) + mask + exp ----
    if (tid < 2 * SEQ) {
        int h = tid / SEQ, s2 = tid % SEQ;
        float ssum = 0.f;
        #pragma unroll
        for (int l = 0; l < NLVL; ++l) {
            float v = __fdividef(s_scores[(h * NLVL + l) * SCST + s2],
                                 s_denom[h * NLVL + l]);
            float v2 = v * v;
            ssum += v2 * v2;
        }
        float A = sqrtf(sqrtf(ssum));
        int m = item_seq[(size_t)b * SEQ + s2];
        s_A[tid] = (m > 0) ? __expf(A) : 0.f;
    }
    __syncthreads();

    // ---- stage 6: weighted sum over s (4-way split), emb re-read (LLC-warm) ----
    {
        int c = tid & 127, qq = tid >> 7;
        int h = c >> 6;
        const float* wv = s_A + h * SEQ + qq * 50;
        const float* eg = embb + (size_t)(qq * 50) * HID + c;
        float acc = 0.f;
        #pragma unroll 10
        for (int s = 0; s < 50; ++s)
            acc += wv[s] * eg[(size_t)s * HID];
        s_red[tid] = acc;
    }
    __syncthreads();

    // ---- stage 7: combine + softmax-2 denominator folded in (wave-local shuffle) ----
    if (tid < HID) {
        int h = tid >> 6;   // whole wave shares h
        const float* row = s_A + h * SEQ;
        float sum = row[lane] + row[lane + 64] + row[lane + 128]
                  + ((lane + 192 < 200) ? row[lane + 192] : 0.f);
        #pragma unroll
        for (int mm = 1; mm < 64; mm <<= 1) sum += __shfl_xor(sum, mm, 64);
        float inv = 1.f / sum;
        float tot = (s_red[tid] + s_red[tid + 128] + s_red[tid + 256] + s_red[tid + 384]) * inv;
        out[(size_t)b * HID + tid] = tot;
    }
}

// ---- fallback (ws too small): proven monolithic fp32 kernel ----
__global__ __launch_bounds__(256) void mixer_fallback(
    const int* __restrict__ item_seq, const float* __restrict__ emb,
    const int* __restrict__ seq_len,
    const float* __restrict__ Wlq, const float* __restrict__ blq,
    const float* __restrict__ Wq,  const float* __restrict__ bq,
    const float* __restrict__ Wk,  const float* __restrict__ bk,
    float* __restrict__ out)
{
    const int b = blockIdx.x, tid = threadIdx.x;
    __shared__ unsigned s_embu[SEQ * 65];
    __shared__ float s_qk[28 * 128];
    __shared__ float s_qb[28];
    __shared__ float s_tmp[2800];
    __shared__ float s_A[400];
    __shared__ float s_red[256];
    __shared__ float s_inv[2];

    {
        const float4* src = (const float4*)(emb + (size_t)b * SEQ * HID);
        for (int i = tid; i < SEQ * 32; i += 256) {
            int row = i >> 5, j = i & 31;
            float4 v = src[i];
            unsigned* dst = s_embu + row * 65 + 2 * j;
            dst[0] = pack_bf(v.x, v.y);
            dst[1] = pack_bf(v.z, v.w);
        }
    }
    const int len = seq_len[b];
    if (tid < HID) {
        float acc = 0.f;
        for (int j = 0; j < NLVL; ++j) {
            int idx = len - (j + 1);
            if (idx < 0) idx = SEQ - 1;
            acc += emb[(size_t)b * SEQ * HID + (size_t)idx * HID + tid];
            s_tmp[j * HID + tid] = acc;
        }
    }
    __syncthreads();
    for (int t = tid; t < NLVL * HID; t += 256) {
        int l = t >> 7, c = t & 127;
        const float* x = s_tmp + l * HID;
        float acc = blq[c];
        #pragma unroll 8
        for (int k = 0; k < HID; ++k) acc += x[k] * Wlq[c * HID + k];
        s_tmp[896 + t] = acc;
    }
    __syncthreads();
    for (int t = tid; t < NLVL * HID; t += 256) {
        int l = t >> 7, c = t & 127;
        const float* x = s_tmp + 896 + l * HID;
        float acc = bq[c];
        #pragma unroll 8
        for (int k = 0; k < HID; ++k) acc += x[k] * Wq[c * HID + k];
        s_tmp[t] = acc;
    }
    __syncthreads();
    for (int o = tid; o < 28 * 128; o += 256) {
        int qrow = o >> 7, c = o & 127;
        int hl = qrow >> 1, par = qrow & 1;
        const float* qv = s_tmp + hl * 64;
        float acc = 0.f;
        #pragma unroll 8
        for (int d2 = 0; d2 < 64; ++d2) acc += qv[d2] * Wk[(par * 64 + d2) * HID + c];
        s_qk[qrow * 128 + c] = acc;
    }
    if (tid < 28) {
        int hl = tid >> 1, par = tid & 1;
        float acc = 0.f;
        for (int d2 = 0; d2 < 64; ++d2) acc += s_tmp[hl * 64 + d2] * bk[par * 64 + d2];
        s_qb[tid] = acc;
    }
    __syncthreads();
    for (int o = tid; o < 700; o += 256) {
        int hl = o / 50, g = o % 50;
        int h = (hl >= 7) ? 1 : 0;
        int rA = h * 100 + g, rB = rA + 50;
        const unsigned* eA = s_embu + rA * 65;
        const unsigned* eB = s_embu + rB * 65;
        const float* k0 = s_qk + (hl * 2) * 128;
        const float* k1 = s_qk + (hl * 2 + 1) * 128;
        float a0 = 0.f, a1 = 0.f, c0a = 0.f, c1a = 0.f;
        #pragma unroll 4
        for (int kk = 0; kk < 64; ++kk) {
            unsigned uA = eA[kk], uB = eB[kk];
            float2 w0 = *(const float2*)(k0 + 2 * kk);
            float2 w1 = *(const float2*)(k1 + 2 * kk);
            float alo = bf_lo(uA), ahi = bf_hi(uA);
            float blo = bf_lo(uB), bhi = bf_hi(uB);
            a0 += alo * w0.x + ahi * w0.y;  a1 += alo * w1.x + ahi * w1.y;
            c0a += blo * w0.x + bhi * w0.y; c1a += blo * w1.x + bhi * w1.y;
        }
        float qb0 = s_qb[hl * 2], qb1 = s_qb[hl * 2 + 1];
        float* row = s_tmp + hl * 200;
        row[2 * g]       = 1.f / (1.f + __expf(-(a0 + qb0)));
        row[2 * g + 1]   = 1.f / (1.f + __expf(-(a1 + qb1)));
        row[2 * g + 100] = 1.f / (1.f + __expf(-(c0a + qb0)));
        row[2 * g + 101] = 1.f / (1.f + __expf(-(c1a + qb1)));
    }
    __syncthreads();
    const int wave = tid >> 6, lane = tid & 63;
    for (int r = wave; r < 14; r += 4) {
        float* row = s_tmp + r * 200;
        float e0 = __expf(row[lane]), e1 = __expf(row[lane + 64]);
        float e2 = __expf(row[lane + 128]);
        float e3 = (lane + 192 < 200) ? __expf(row[lane + 192]) : 0.f;
        float sum = e0 + e1 + e2 + e3;
        #pragma unroll
        for (int m = 1; m < 64; m <<= 1) sum += __shfl_xor(sum, m, 64);
        float inv = 1.f / sum;
        row[lane] = e0 * inv; row[lane + 64] = e1 * inv; row[lane + 128] = e2 * inv;
        if (lane + 192 < 200) row[lane + 192] = e3 * inv;
    }
    __syncthreads();
    for (int o = tid; o < 2 * SEQ; o += 256) {
        int h = o / SEQ, s2 = o % SEQ;
        float ssum = 0.f;
        #pragma unroll
        for (int l = 0; l < NLVL; ++l) {
            float v = s_tmp[(h * NLVL + l) * 200 + s2];
            float v2 = v * v; ssum += v2 * v2;
        }
        float A = sqrtf(sqrtf(ssum));
        s_A[o] = (item_seq[(size_t)b * SEQ + s2] > 0) ? __expf(A) : 0.f;
    }
    __syncthreads();
    if (wave < 2) {
        const float* row = s_A + wave * SEQ;
        float sum = row[lane] + row[lane + 64] + row[lane + 128]
                  + ((lane + 192 < 200) ? row[lane + 192] : 0.f);
        #pragma unroll
        for (int m = 1; m < 64; m <<= 1) sum += __shfl_xor(sum, m, 64);
        if (lane == 0) s_inv[wave] = 1.f / sum;
    }
    __syncthreads();
    {
        int c = tid & 127, halfb = tid >> 7;
        int h = c >> 6;
        const float* wv = s_A + h * SEQ + halfb * 100;
        float acc = 0.f;
        #pragma unroll 4
        for (int s2 = 0; s2 < 100; ++s2) {
            unsigned u = s_embu[(halfb * 100 + s2) * 65 + (c >> 1)];
            acc += wv[s2] * ((c & 1) ? bf_hi(u) : bf_lo(u));
        }
        s_red[tid] = acc;
    }
    __syncthreads();
    if (tid < HID) {
        int h = tid >> 6;
        out[(size_t)b * HID + tid] = (s_red[tid] + s_red[tid + 128]) * s_inv[h];
    }
}

extern "C" void kernel_launch(void* const* d_in, const int* in_sizes, int n_in,
                              void* d_out, int out_size, void* d_ws, size_t ws_size,
                              hipStream_t stream) {
    const int* item_seq = (const int*)d_in[0];
    const float* emb    = (const float*)d_in[1];
    const int* seq_len  = (const int*)d_in[2];
    const float* Wlq    = (const float*)d_in[3];
    const float* blq    = (const float*)d_in[4];
    const float* Wq     = (const float*)d_in[5];
    const float* bq     = (const float*)d_in[6];
    const float* Wk     = (const float*)d_in[7];
    const float* bk     = (const float*)d_in[8];
    float* out          = (float*)d_out;
    const int B = in_sizes[2];  // 2048

    if (ws_size >= (size_t)WS_WORDS * 4) {
        float* ws = (float*)d_ws;
        precomp0<<<64, 256, 0, stream>>>(Wlq, blq, Wq, bq, ws);
        precomp1<<<261, 256, 0, stream>>>(Wk, bk, ws);
        mixer_main<<<B, 512, 0, stream>>>(item_seq, emb, seq_len, ws, out);
    } else {
        mixer_fallback<<<B, 256, 0, stream>>>(item_seq, emb, seq_len, Wlq, blq, Wq, bq, Wk, bk, out);
    }
}